// Round 7
// baseline (155.501 us; speedup 1.0000x reference)
//
#include <hip/hip_runtime.h>
#include <hip/hip_bf16.h>
#include <math.h>

#define Bq   8
#define DINq 256
#define Nq   2048

typedef __attribute__((ext_vector_type(8))) short bf16x8v;
typedef __attribute__((ext_vector_type(4))) float f32x4v;

__device__ __forceinline__ unsigned short f2bf(float f) {
  union { float f; unsigned u; } v; v.f = f;
  unsigned r = v.u + 0x7fffu + ((v.u >> 16) & 1u);
  return (unsigned short)(r >> 16);
}
__device__ __forceinline__ float bf2f(unsigned short h) {
  union { unsigned u; float f; } v; v.u = ((unsigned)h) << 16;
  return v.f;
}

__device__ __forceinline__ void gld_lds16(const void* g, void* l) {
  __builtin_amdgcn_global_load_lds(
      (const __attribute__((address_space(1))) unsigned int*)g,
      (__attribute__((address_space(3))) unsigned int*)l, 16, 0, 0);
}

// ---- w123[k] = (W^T a1)[k], (W^T a2)[k], (W^T a3)[k] ----
__global__ void k_prep(const float* __restrict__ W, const float* __restrict__ a,
                       float* __restrict__ w123) {
  int k = threadIdx.x;
  float s1 = 0.f, s2 = 0.f, s3 = 0.f;
  for (int d = 0; d < DINq; ++d) {
    float w = W[d * DINq + k];
    s1 += w * a[d];
    s2 += w * a[DINq + d];
    s3 += w * a[2 * DINq + d];
  }
  w123[k] = s1; w123[DINq + k] = s2; w123[2 * DINq + k] = s3;
}

// ---- Whi/Wlo bf16 split of W (row-major [d][k], no transpose needed) ----
__global__ void k_wsplit(const float* __restrict__ W, unsigned short* __restrict__ Whi,
                         unsigned short* __restrict__ Wlo) {
  int idx = blockIdx.x * 256 + threadIdx.x;
  float w = W[idx];
  unsigned short h = f2bf(w);
  Whi[idx] = h;
  Wlo[idx] = f2bf(w - bf2f(h));
}

// ---- t, si, sb per (b,i): dot of x column with w123 vectors ----
__global__ void k_tsisb(const float* __restrict__ x, const float* __restrict__ w123,
                        float* __restrict__ tA, float* __restrict__ siA,
                        float* __restrict__ sbA) {
  int b = blockIdx.y;
  int il = threadIdx.x & 63;
  int i = blockIdx.x * 64 + il;
  int ks = (threadIdx.x >> 6) * 64;
  float a1 = 0.f, a2 = 0.f, a3 = 0.f;
  for (int k = ks; k < ks + 64; ++k) {
    float xv = x[((size_t)b * DINq + k) * Nq + i];
    a1 += xv * w123[k];
    a2 += xv * w123[DINq + k];
    a3 += xv * w123[2 * DINq + k];
  }
  __shared__ float r1[256], r2[256], r3[256];
  r1[threadIdx.x] = a1; r2[threadIdx.x] = a2; r3[threadIdx.x] = a3;
  __syncthreads();
  if (threadIdx.x < 64) {
    int l = threadIdx.x;
    float v1 = r1[l] + r1[64 + l] + r1[128 + l] + r1[192 + l];
    float v2 = r2[l] + r2[64 + l] + r2[128 + l] + r2[192 + l];
    float v3 = r3[l] + r3[64 + l] + r3[128 + l] + r3[192 + l];
    int ii = blockIdx.x * 64 + l;
    siA[(size_t)b * Nq + ii] = v1;
    sbA[(size_t)b * Nq + ii] = v2;
    tA[(size_t)b * Nq + ii] = v3;
  }
}

// ---- y^T rows: yt[(b,i)][k] = t[b,i]*x[b,k,i], bf16 hi/lo (transpose via LDS) ----
__global__ __launch_bounds__(256) void k_yT(const float* __restrict__ x,
                    const float* __restrict__ tA, unsigned short* __restrict__ yhi,
                    unsigned short* __restrict__ ylo) {
  __shared__ unsigned lds[64][129];  // packed (hi | lo<<16), +1 pad
  __shared__ float tl[64];
  const int tid = threadIdx.x;
  const int i0 = blockIdx.x * 64;
  const int b = blockIdx.y;
  if (tid < 64) tl[tid] = tA[(size_t)b * Nq + i0 + tid];
  for (int kh = 0; kh < 2; ++kh) {
    __syncthreads();
#pragma unroll 4
    for (int n = 0; n < 32; ++n) {
      int idx = n * 256 + tid;
      int k = idx >> 6, i = idx & 63;
      float xv = x[((size_t)b * DINq + kh * 128 + k) * Nq + i0 + i];
      float yv = tl[i] * xv;
      unsigned short h = f2bf(yv);
      unsigned short l = f2bf(yv - bf2f(h));
      lds[i][k] = (unsigned)h | ((unsigned)l << 16);
    }
    __syncthreads();
    const int i = tid >> 2, kq = (tid & 3) * 32;
    size_t base = ((size_t)b * Nq + i0 + i) * DINq + kh * 128 + kq;
#pragma unroll
    for (int g = 0; g < 8; ++g) {
      unsigned short hh[4], ll[4];
#pragma unroll
      for (int e = 0; e < 4; ++e) {
        unsigned v = lds[i][kq + g * 4 + e];
        hh[e] = (unsigned short)(v & 0xffff);
        ll[e] = (unsigned short)(v >> 16);
      }
      *(ushort4*)&yhi[base + g * 4] = make_ushort4(hh[0], hh[1], hh[2], hh[3]);
      *(ushort4*)&ylo[base + g * 4] = make_ushort4(ll[0], ll[1], ll[2], ll[3]);
    }
  }
}

// ---- X^T[(b,d)][i] = sum_k W[d,k]*y[(b,i)][k] via MFMA; K=3x256 segments ----
// Exact clone of k_gemm skeleton: A-rows = yt (64), B-rows = W (128=d-half).
__global__ __launch_bounds__(256, 2) void k_hX2(const unsigned short* __restrict__ yhi,
                    const unsigned short* __restrict__ ylo,
                    const unsigned short* __restrict__ Whi,
                    const unsigned short* __restrict__ Wlo,
                    unsigned short* __restrict__ Xhi, unsigned short* __restrict__ Xlo) {
  __shared__ __align__(16) unsigned short As[3][64 * 32];   // 12 KB
  __shared__ __align__(16) unsigned short Bs[3][128 * 32];  // 24 KB
  __shared__ unsigned xout[128][65];                        // 33.3 KB
  const int tid = threadIdx.x;
  const int lane = tid & 63;
  const int wc = tid >> 6;          // wave = d-quarter (32 d)
  const int wg = blockIdx.x;
  const int b = wg >> 6;
  const int rem = wg & 63;
  const int it = rem >> 1, dh = rem & 1;
  const int r15 = lane & 15, kg = lane >> 4;
  const int kb = 16 * (kg ^ ((r15 >> 1) & 3));

  f32x4v acc[4][2];
#pragma unroll
  for (int m = 0; m < 4; ++m)
#pragma unroll
    for (int n = 0; n < 2; ++n) acc[m][n] = (f32x4v)0.f;

  auto STAGE = [&](int buf, int t) {
    const int seg = t >> 3;
    const int k0 = (t & 7) * 32;
    const unsigned short* ys = (seg == 1) ? ylo : yhi;
    const unsigned short* wsrc = (seg == 2) ? Wlo : Whi;
    {
      const int row = tid >> 2, q = tid & 3;
      const int kc = 8 * (q ^ ((row >> 1) & 3));
      gld_lds16(&ys[((size_t)b * Nq + it * 64 + row) * DINq + k0 + kc], &As[buf][tid * 8]);
    }
#pragma unroll
    for (int l = 0; l < 2; ++l) {
      const int pc = l * 256 + tid;
      const int row = pc >> 2, q = pc & 3;
      const int kc = 8 * (q ^ ((row >> 1) & 3));
      gld_lds16(&wsrc[(size_t)(dh * 128 + row) * DINq + k0 + kc], &Bs[buf][pc * 8]);
    }
  };

  constexpr int NT = 24;  // 3 segments x 8 K-steps
  STAGE(0, 0);
  STAGE(1, 1);
  int cb = 0, sb2 = 2;
  for (int t = 0; t < NT; ++t) {
    if (t + 1 < NT) {
      asm volatile("s_waitcnt vmcnt(3)" ::: "memory");
    } else {
      asm volatile("s_waitcnt vmcnt(0)" ::: "memory");
    }
    __builtin_amdgcn_sched_barrier(0);
    __builtin_amdgcn_s_barrier();
    __builtin_amdgcn_sched_barrier(0);
    if (t + 2 < NT) STAGE(sb2, t + 2);

    const char* Ab = (const char*)&As[cb][0];
    const char* Bb = (const char*)&Bs[cb][0];
    bf16x8v af[4], bf[2];
#pragma unroll
    for (int m = 0; m < 4; ++m)
      af[m] = *(const bf16x8v*)(Ab + (m * 16 + r15) * 64 + kb);
#pragma unroll
    for (int n = 0; n < 2; ++n)
      bf[n] = *(const bf16x8v*)(Bb + (wc * 32 + n * 16 + r15) * 64 + kb);
    __builtin_amdgcn_s_setprio(1);
#pragma unroll
    for (int m = 0; m < 4; ++m)
#pragma unroll
      for (int n = 0; n < 2; ++n)
        acc[m][n] = __builtin_amdgcn_mfma_f32_16x16x32_bf16(af[m], bf[n], acc[m][n], 0, 0, 0);
    __builtin_amdgcn_s_setprio(0);
    cb = (cb == 2) ? 0 : cb + 1;
    sb2 = (sb2 == 2) ? 0 : sb2 + 1;
  }

  // D[i_loc][d_loc]: row = i, col = d. Split hi/lo, repack in LDS, store coalesced.
  const int re = (lane >> 4) * 4, ce = lane & 15;
#pragma unroll
  for (int m = 0; m < 4; ++m)
#pragma unroll
    for (int n = 0; n < 2; ++n) {
      const int dl = wc * 32 + n * 16 + ce;
#pragma unroll
      for (int r = 0; r < 4; ++r) {
        float Xv = acc[m][n][r];
        unsigned short h = f2bf(Xv);
        unsigned short l = f2bf(Xv - bf2f(h));
        xout[dl][m * 16 + re + r] = (unsigned)h | ((unsigned)l << 16);
      }
    }
  __syncthreads();
  const int d = tid >> 1, ih = (tid & 1) * 32;
  size_t base = ((size_t)b * DINq + dh * 128 + d) * Nq + it * 64 + ih;
#pragma unroll
  for (int g = 0; g < 8; ++g) {
    unsigned short hh[4], ll[4];
#pragma unroll
    for (int e = 0; e < 4; ++e) {
      unsigned v = xout[d][ih + g * 4 + e];
      hh[e] = (unsigned short)(v & 0xffff);
      ll[e] = (unsigned short)(v >> 16);
    }
    *(ushort4*)&Xhi[base + g * 4] = make_ushort4(hh[0], hh[1], hh[2], hh[3]);
    *(ushort4*)&Xlo[base + g * 4] = make_ushort4(ll[0], ll[1], ll[2], ll[3]);
  }
}

// ---- Mb[i][j] = (adj!=0 && i!=j) ? 1.0bf16 : 0 ; bm = adj!=0 bitmask ----
__global__ void k_mask(const int* __restrict__ adj, unsigned short* __restrict__ Mb,
                       unsigned* __restrict__ bm) {
  int wg = blockIdx.x * 256 + threadIdx.x;
  int i = wg >> 6, w = wg & 63, j0 = w * 32;
  const int4* ap = (const int4*)&adj[(size_t)i * Nq + j0];
  unsigned bits = 0;
  unsigned short mv[32];
#pragma unroll
  for (int q = 0; q < 8; ++q) {
    int4 a = ap[q];
    int av[4] = {a.x, a.y, a.z, a.w};
#pragma unroll
    for (int e = 0; e < 4; ++e) {
      int j = j0 + q * 4 + e;
      bool nz = (av[e] != 0);
      if (nz) bits |= 1u << (q * 4 + e);
      mv[q * 4 + e] = (nz && j != i) ? (unsigned short)0x3F80 : (unsigned short)0;
    }
  }
  ushort4* mp = (ushort4*)&Mb[(size_t)i * Nq + j0];
#pragma unroll
  for (int q = 0; q < 8; ++q)
    mp[q] = make_ushort4(mv[q * 4], mv[q * 4 + 1], mv[q * 4 + 2], mv[q * 4 + 3]);
  bm[wg] = bits;
}

// ---- GEMM: tile 256(M)x128(C), BK=32 tri-buffer counted vmcnt, K-split x2,
//      z-split hi/lo, XCD-swizzled grid, fused sjv-partial epilogue (X-based) ----
__global__ __launch_bounds__(256, 2) void k_gemm(const unsigned short* __restrict__ Mb,
                                                 const unsigned short* __restrict__ Xhi,
                                                 const unsigned short* __restrict__ Xlo,
                                                 float* __restrict__ sjp) {
  __shared__ __align__(16) unsigned short As[3][256 * 32];
  __shared__ __align__(16) unsigned short Bs[3][128 * 32];
  const int tid = threadIdx.x;
  const int lane = tid & 63;
  const int wave = tid >> 6;
  const int wm = wave >> 1, wc = wave & 1;
  const int wg = blockIdx.x;
  const int lin = (wg & 7) * 64 + (wg >> 3);
  const int mt = lin >> 6;
  const int rem = lin & 63;
  const int ks = rem >> 5;
  const int z = (rem >> 4) & 1;
  const int ct = rem & 15;
  const int i0 = mt * 256, c0 = ct * 128, kbase = ks * 1024;
  const unsigned short* __restrict__ Xp = z ? Xlo : Xhi;
  const int r15 = lane & 15, kg = lane >> 4;
  const int kb = 16 * (kg ^ ((r15 >> 1) & 3));  // conflict-free swizzle

  f32x4v acc[8][4];
#pragma unroll
  for (int m = 0; m < 8; ++m)
#pragma unroll
    for (int n = 0; n < 4; ++n) acc[m][n] = (f32x4v)0.f;

  auto STAGE = [&](int buf, int t) {
    const int k0 = kbase + t * 32;
#pragma unroll
    for (int l = 0; l < 4; ++l) {
      const int pc = l * 256 + tid;
      const int row = pc >> 2, q = pc & 3;
      const int kc = 8 * (q ^ ((row >> 1) & 3));
      gld_lds16(&Mb[(size_t)(i0 + row) * Nq + k0 + kc], &As[buf][pc * 8]);
    }
#pragma unroll
    for (int l = 0; l < 2; ++l) {
      const int pc = l * 256 + tid;
      const int row = pc >> 2, q = pc & 3;
      const int kc = 8 * (q ^ ((row >> 1) & 3));
      gld_lds16(&Xp[(size_t)(c0 + row) * Nq + k0 + kc], &Bs[buf][pc * 8]);
    }
  };

  constexpr int NT = 32;  // 1024 / 32
  STAGE(0, 0);
  STAGE(1, 1);
  int cb = 0, sb2 = 2;
  for (int t = 0; t < NT; ++t) {
    if (t + 1 < NT) {
      asm volatile("s_waitcnt vmcnt(6)" ::: "memory");
    } else {
      asm volatile("s_waitcnt vmcnt(0)" ::: "memory");
    }
    __builtin_amdgcn_sched_barrier(0);
    __builtin_amdgcn_s_barrier();
    __builtin_amdgcn_sched_barrier(0);
    if (t + 2 < NT) STAGE(sb2, t + 2);

    const char* Ab = (const char*)&As[cb][0];
    const char* Bb = (const char*)&Bs[cb][0];
    bf16x8v af[8], bf[4];
#pragma unroll
    for (int m = 0; m < 8; ++m)
      af[m] = *(const bf16x8v*)(Ab + (wm * 128 + m * 16 + r15) * 64 + kb);
#pragma unroll
    for (int n = 0; n < 4; ++n)
      bf[n] = *(const bf16x8v*)(Bb + (wc * 64 + n * 16 + r15) * 64 + kb);
    __builtin_amdgcn_s_setprio(1);
#pragma unroll
    for (int m = 0; m < 8; ++m)
#pragma unroll
      for (int n = 0; n < 4; ++n)
        acc[m][n] = __builtin_amdgcn_mfma_f32_16x16x32_bf16(af[m], bf[n], acc[m][n], 0, 0, 0);
    __builtin_amdgcn_s_setprio(0);
    cb = (cb == 2) ? 0 : cb + 1;
    sb2 = (sb2 == 2) ? 0 : sb2 + 1;
  }

  // Fused epilogue: partial = sum_d acc * (Xhi+Xlo); division by t in k_sjsum.
  const int b = c0 >> 8;
  const int re = (lane >> 4) * 4, ce = lane & 15;
  float s[8][4];
#pragma unroll
  for (int m = 0; m < 8; ++m)
#pragma unroll
    for (int r = 0; r < 4; ++r) s[m][r] = 0.f;
#pragma unroll
  for (int n = 0; n < 4; ++n) {
    const size_t xrow = (size_t)(c0 + wc * 64 + n * 16 + ce) * Nq;
#pragma unroll
    for (int m = 0; m < 8; ++m) {
      const size_t ib = xrow + i0 + wm * 128 + m * 16 + re;
      ushort4 xh = *(const ushort4*)&Xhi[ib];
      ushort4 xl = *(const ushort4*)&Xlo[ib];
      s[m][0] += acc[m][n][0] * (bf2f(xh.x) + bf2f(xl.x));
      s[m][1] += acc[m][n][1] * (bf2f(xh.y) + bf2f(xl.y));
      s[m][2] += acc[m][n][2] * (bf2f(xh.z) + bf2f(xl.z));
      s[m][3] += acc[m][n][3] * (bf2f(xh.w) + bf2f(xl.w));
    }
  }
#pragma unroll
  for (int o = 1; o < 16; o <<= 1) {
#pragma unroll
    for (int m = 0; m < 8; ++m)
#pragma unroll
      for (int r = 0; r < 4; ++r) s[m][r] += __shfl_xor(s[m][r], o, 64);
  }
  if (ce == 0) {
    const int slice = ks * 8 + z * 4 + (ct & 1) * 2 + wc;
    float* sp = sjp + ((size_t)slice * Bq + b) * Nq;
#pragma unroll
    for (int m = 0; m < 8; ++m)
#pragma unroll
      for (int r = 0; r < 4; ++r)
        sp[i0 + wm * 128 + m * 16 + re + r] = s[m][r];
  }
}

// ---- sjv[b,i] = sb[b,i] + (sum of 16 partial slices) / t[b,i] ----
__global__ void k_sjsum(const float* __restrict__ sbA, const float* __restrict__ tA,
                        const float* __restrict__ sjp, float* __restrict__ sjvA) {
  int idx = blockIdx.x * 256 + threadIdx.x;
  float s = 0.f;
#pragma unroll
  for (int sl = 0; sl < 16; ++sl) s += sjp[(size_t)sl * Bq * Nq + idx];
  sjvA[idx] = sbA[idx] + s / tA[idx];
}

// ---- out[b,i,:] = softmax_j( mask(bm, lrelu(si[b,i] + sjv[b,j])) ) ----
__global__ void k_softmax(const unsigned* __restrict__ bm, const float* __restrict__ siA,
                          const float* __restrict__ sjvA, float* __restrict__ out) {
  const int b = blockIdx.y, i = blockIdx.x, tid = threadIdx.x;
  const float siv = siA[(size_t)b * Nq + i];
  const unsigned* brow = bm + (size_t)i * 64;
  const float* sjb = sjvA + (size_t)b * Nq;
  const int bit = tid & 31;
  float sc[8];
  float mx = -3.0e38f;
#pragma unroll
  for (int s = 0; s < 8; ++s) {
    int j = s * 256 + tid;
    float v = siv + sjb[j];
    v = v > 0.f ? v : 0.2f * v;
    unsigned wv = brow[j >> 5];
    v = ((wv >> bit) & 1u) ? v : -9.0e15f;
    sc[s] = v;
    mx = fmaxf(mx, v);
  }
#pragma unroll
  for (int o = 32; o >= 1; o >>= 1) mx = fmaxf(mx, __shfl_xor(mx, o, 64));
  __shared__ float redm[4], reds[4];
  const int wave = tid >> 6, lane = tid & 63;
  if (lane == 0) redm[wave] = mx;
  __syncthreads();
  mx = fmaxf(fmaxf(redm[0], redm[1]), fmaxf(redm[2], redm[3]));
  float sum = 0.f, ex[8];
#pragma unroll
  for (int s = 0; s < 8; ++s) { ex[s] = expf(sc[s] - mx); sum += ex[s]; }
#pragma unroll
  for (int o = 32; o >= 1; o >>= 1) sum += __shfl_xor(sum, o, 64);
  if (lane == 0) reds[wave] = sum;
  __syncthreads();
  sum = reds[0] + reds[1] + reds[2] + reds[3];
  float inv = 1.f / sum;
  float* orow = out + ((size_t)b * Nq + i) * Nq;
#pragma unroll
  for (int s = 0; s < 8; ++s) orow[s * 256 + tid] = ex[s] * inv;
}

extern "C" void kernel_launch(void* const* d_in, const int* in_sizes, int n_in,
                              void* d_out, int out_size, void* d_ws, size_t ws_size,
                              hipStream_t stream) {
  const float* x = (const float*)d_in[0];
  const int* adj = (const int*)d_in[1];
  const float* W = (const float*)d_in[2];
  const float* a = (const float*)d_in[3];
  float* out = (float*)d_out;

  char* ws = (char*)d_ws;
  size_t off = 0;
  auto alloc = [&](size_t bytes) -> void* {
    void* p = ws + off;
    off += (bytes + 255) & ~(size_t)255;
    return p;
  };
  float* w123 = (float*)alloc(3 * DINq * sizeof(float));
  float* tA = (float*)alloc((size_t)Bq * Nq * sizeof(float));
  float* siA = (float*)alloc((size_t)Bq * Nq * sizeof(float));
  float* sbA = (float*)alloc((size_t)Bq * Nq * sizeof(float));
  float* sjvA = (float*)alloc((size_t)Bq * Nq * sizeof(float));
  float* sjp = (float*)alloc((size_t)16 * Bq * Nq * sizeof(float));
  unsigned short* Whi = (unsigned short*)alloc((size_t)DINq * DINq * 2);
  unsigned short* Wlo = (unsigned short*)alloc((size_t)DINq * DINq * 2);
  unsigned short* yhi = (unsigned short*)alloc((size_t)Bq * Nq * DINq * 2);
  unsigned short* ylo = (unsigned short*)alloc((size_t)Bq * Nq * DINq * 2);
  unsigned short* Xhi = (unsigned short*)alloc((size_t)Nq * Nq * 2);
  unsigned short* Xlo = (unsigned short*)alloc((size_t)Nq * Nq * 2);
  unsigned short* Mb = (unsigned short*)alloc((size_t)Nq * Nq * 2);
  unsigned* bm = (unsigned*)alloc((size_t)Nq * 64 * sizeof(unsigned));

  k_prep<<<dim3(1), dim3(256), 0, stream>>>(W, a, w123);
  k_wsplit<<<dim3(DINq * DINq / 256), dim3(256), 0, stream>>>(W, Whi, Wlo);
  k_tsisb<<<dim3(Nq / 64, Bq), dim3(256), 0, stream>>>(x, w123, tA, siA, sbA);
  k_yT<<<dim3(Nq / 64, Bq), dim3(256), 0, stream>>>(x, tA, yhi, ylo);
  k_mask<<<dim3(Nq * 64 / 256), dim3(256), 0, stream>>>(adj, Mb, bm);
  k_hX2<<<dim3(512), dim3(256), 0, stream>>>(yhi, ylo, Whi, Wlo, Xhi, Xlo);
  k_gemm<<<dim3(512), dim3(256), 0, stream>>>(Mb, Xhi, Xlo, sjp);
  k_sjsum<<<dim3(Bq * Nq / 256), dim3(256), 0, stream>>>(sbA, tA, sjp, sjvA);
  k_softmax<<<dim3(Nq, Bq), dim3(256), 0, stream>>>(bm, siA, sjvA, out);
}